// Round 4
// baseline (455.060 us; speedup 1.0000x reference)
//
#include <hip/hip_runtime.h>
#include <hip/hip_bf16.h>

// MultiheadAttention_ViTNO: B=8, P=256, S=8x8(=64), D=256, NHEAD=8, DK=32, SCALE=64
// R4: k1 restructured — 64-token tile (halves W L2 traffic), x cast to bf16
// DURING reg-staging into a swizzled 32KB LDS tile (1 ds_read_b128 per A-frag,
// zero cvt in K-loop, 48 MFMA : 12 W-loads per kk = 4:1), 2 blocks/CU overlap.
// R3 lesson: k1 was latency-bound (issue work ~16us vs 185us measured); the
// 2^21 conflict cycles were the global_load_lds DMA-write side (16cyc/instr).

typedef __bf16 bf16;
typedef __attribute__((ext_vector_type(8))) __bf16 bf16x8;
typedef __attribute__((ext_vector_type(4))) float floatx4;
typedef __attribute__((ext_vector_type(8))) unsigned short ushort8;

#define CDIM 2048             // 64*32 flattened (sxy, dk) per head

static __device__ __forceinline__ floatx4 mfma16(bf16x8 a, bf16x8 b, floatx4 c) {
  return __builtin_amdgcn_mfma_f32_16x16x32_bf16(a, b, c, 0, 0, 0);
}

// ---------------- K0: weight prep ----------------
// Wp: fragment-linear pack of Wq/Wk/Wv (head-permuted rows i'=n*32+dk):
//   Wp[((mat*8 + kk)*16 + rowblk)*64 + lane]*8 ; lane=(h,cl):
//   element = Wperm[rowblk*16+cl][kk*32+8h+j]
// WOp: row-major [j][i'-permuted col] for k3. biasp[3][256] permuted.
__global__ __launch_bounds__(256) void k0_prep(
    const float* __restrict__ Wq, const float* __restrict__ bq,
    const float* __restrict__ Wk, const float* __restrict__ bk,
    const float* __restrict__ Wv, const float* __restrict__ bv,
    const float* __restrict__ Wo,
    bf16* __restrict__ Wp, bf16* __restrict__ WOp, float* __restrict__ biasp)
{
  const int bid = blockIdx.x, tid = threadIdx.x;
  if (bid < 32) {
    int g = bid * 256 + tid;            // 0..8191 : (kk, rowblk, lane)
    int lane = g & 63, rowblk = (g >> 6) & 15, kk = g >> 10;
    int h = lane >> 4, cl = lane & 15;
    int ip = rowblk * 16 + cl;          // i' = n*32+dk
    int isrc = ((ip & 31) << 3) | (ip >> 5);
    int d0 = kk * 32 + 8 * h;
#pragma unroll
    for (int mat = 0; mat < 3; mat++) {
      const float* W = (mat == 0) ? Wq : (mat == 1) ? Wk : Wv;
      bf16x8 v;
#pragma unroll
      for (int j = 0; j < 8; j++) v[j] = (bf16)W[isrc * 256 + d0 + j];
      *reinterpret_cast<bf16x8*>(Wp + ((size_t)mat * 8192 + g) * 8) = v;
    }
  } else {
    int g = (bid - 32) * 256 + tid;     // 0..8191
    int row = g >> 5;
    int c0 = (g & 31) * 8;
#pragma unroll
    for (int j = 0; j < 8; j++) {
      int c = c0 + j;
      WOp[row * 256 + c] = (bf16)Wo[row * 256 + (((c & 31) << 3) | (c >> 5))];
    }
    if (g < 256) {
      int bs = ((g & 31) << 3) | (g >> 5);
      biasp[g] = bq[bs]; biasp[256 + g] = bk[bs]; biasp[512 + g] = bv[bs];
    }
  }
}

// ---------------- K1: fused QKV projection ----------------
// grid 2048; block 256 (4 waves = 4 col-quadrants). Tile: 64 tokens x 256 cols x 3 mats.
// Out token-major: Q/K/V[t][i'] bf16, t=(b,p,sxy).
__global__ __launch_bounds__(256, 2) void k1_qkv(
    const float* __restrict__ x, const bf16* __restrict__ Wp,
    const float* __restrict__ biasp,
    bf16* __restrict__ Qt, bf16* __restrict__ Kt, bf16* __restrict__ Vt)
{
  __shared__ bf16 xsb[64 * 256];        // 32KB, granule-XOR-swizzled
  const int t0 = blockIdx.x * 64;
  const int tid = threadIdx.x;
  const int lane = tid & 63;
  const int wq = tid >> 6;              // wave = col quadrant
  const int h = lane >> 4, cl = lane & 15;
  const int c7 = cl & 7;

  // stage: 2048 granules (16B); granule G: row=G>>5, coalesced fp32 src,
  // cvt to bf16, write to physical granule (G&~7)|((G^row)&7)
#pragma unroll
  for (int k = 0; k < 8; ++k) {
    int G = k * 256 + tid;
    int row = G >> 5;
    const float* sp = x + (size_t)(t0 + row) * 256 + (G & 31) * 8;
    floatx4 f0 = *reinterpret_cast<const floatx4*>(sp);
    floatx4 f1 = *reinterpret_cast<const floatx4*>(sp + 4);
    bf16x8 v;
#pragma unroll
    for (int j = 0; j < 4; j++) { v[j] = (bf16)f0[j]; v[4 + j] = (bf16)f1[j]; }
    int Gp = (G & ~7) | ((G ^ row) & 7);
    *reinterpret_cast<bf16x8*>(&xsb[Gp * 8]) = v;
  }
  __syncthreads();

  floatx4 acc[3][4][4];
#pragma unroll
  for (int m = 0; m < 3; m++)
#pragma unroll
    for (int i = 0; i < 4; i++)
#pragma unroll
      for (int j = 0; j < 4; j++) acc[m][i][j] = (floatx4)0.0f;

#pragma unroll 2
  for (int kk = 0; kk < 8; ++kk) {
    bf16x8 a[4];
#pragma unroll
    for (int mt = 0; mt < 4; mt++) {
      int rr = mt * 16 + cl;            // rr&7 == c7
      int G = rr * 32 + kk * 4 + h;
      int Gp = (G & ~7) | ((G ^ c7) & 7);
      a[mt] = *reinterpret_cast<const bf16x8*>(&xsb[Gp * 8]);
    }
#pragma unroll
    for (int mat = 0; mat < 3; mat++) {
#pragma unroll
      for (int nt = 0; nt < 4; nt++) {
        const bf16* wptr = Wp + ((size_t)((mat * 8 + kk) * 16 + (wq * 4 + nt)) * 64 + lane) * 8;
        bf16x8 b8 = *reinterpret_cast<const bf16x8*>(wptr);
#pragma unroll
        for (int mt = 0; mt < 4; mt++)
          acc[mat][mt][nt] = mfma16(a[mt], b8, acc[mat][mt][nt]);
      }
    }
  }

  // token-major epilogue (32B-contiguous per 16 cl lanes)
#pragma unroll
  for (int mat = 0; mat < 3; mat++) {
    bf16* out = (mat == 0) ? Qt : (mat == 1) ? Kt : Vt;
#pragma unroll
    for (int nt = 0; nt < 4; nt++) {
      const int ip = 64 * wq + nt * 16 + cl;
      const float bb = biasp[mat * 256 + ip];
#pragma unroll
      for (int mt = 0; mt < 4; mt++)
#pragma unroll
        for (int r = 0; r < 4; r++) {
          int t = t0 + mt * 16 + 4 * h + r;
          out[(size_t)t * 256 + ip] = (bf16)(acc[mat][mt][nt][r] + bb);
        }
    }
  }
}

// ---------------- K2a: scores + softmax ----------------
// grid 512 (= 64 bn * 8 ptiles of 32); block 256. attn[bn][p][q] bf16.
__global__ __launch_bounds__(256) void k2a_scores(
    const bf16* __restrict__ Qt, const bf16* __restrict__ Kt,
    bf16* __restrict__ attn)
{
  const int bx = blockIdx.x;
  const int bn = bx >> 3;
  const int p0 = (bx & 7) * 32;
  const int b = bn >> 3, n = bn & 7;
  const int lane = threadIdx.x & 63;
  const int wv = threadIdx.x >> 6;
  const int h = lane >> 4, cl = lane & 15;

  const bf16* qp[2];
#pragma unroll
  for (int mt = 0; mt < 2; mt++)
    qp[mt] = Qt + (size_t)((b * 256 + p0 + mt * 16 + cl) * 64) * 256 + n * 32 + 8 * h;
  const bf16* kp[4];
#pragma unroll
  for (int nt = 0; nt < 4; nt++)
    kp[nt] = Kt + (size_t)((b * 256 + 64 * wv + nt * 16 + cl) * 64) * 256 + n * 32 + 8 * h;

  floatx4 acc[2][4];
#pragma unroll
  for (int i = 0; i < 2; i++)
#pragma unroll
    for (int j = 0; j < 4; j++) acc[i][j] = (floatx4)0.0f;

#pragma unroll 4
  for (int ks = 0; ks < 64; ks++) {
    bf16x8 a[2], bb[4];
#pragma unroll
    for (int mt = 0; mt < 2; mt++) {
      a[mt] = *reinterpret_cast<const bf16x8*>(qp[mt]); qp[mt] += 256;
    }
#pragma unroll
    for (int nt = 0; nt < 4; nt++) {
      bb[nt] = *reinterpret_cast<const bf16x8*>(kp[nt]); kp[nt] += 256;
    }
#pragma unroll
    for (int nt = 0; nt < 4; nt++)
#pragma unroll
      for (int mt = 0; mt < 2; mt++) acc[mt][nt] = mfma16(a[mt], bb[nt], acc[mt][nt]);
  }

  __shared__ float redmax[4][32];
  __shared__ float redsum[4][32];

  float pm[2][4];
#pragma unroll
  for (int mt = 0; mt < 2; mt++)
#pragma unroll
    for (int r = 0; r < 4; r++)
      pm[mt][r] = fmaxf(fmaxf(acc[mt][0][r], acc[mt][1][r]),
                        fmaxf(acc[mt][2][r], acc[mt][3][r]));
#pragma unroll
  for (int off = 1; off < 16; off <<= 1)
#pragma unroll
    for (int mt = 0; mt < 2; mt++)
#pragma unroll
      for (int r = 0; r < 4; r++)
        pm[mt][r] = fmaxf(pm[mt][r], __shfl_xor(pm[mt][r], off, 64));
  if (cl == 0) {
#pragma unroll
    for (int mt = 0; mt < 2; mt++)
#pragma unroll
      for (int r = 0; r < 4; r++) redmax[wv][mt * 16 + 4 * h + r] = pm[mt][r];
  }
  __syncthreads();

  float gm[2][4], ps[2][4];
#pragma unroll
  for (int mt = 0; mt < 2; mt++)
#pragma unroll
    for (int r = 0; r < 4; r++) {
      int row = mt * 16 + 4 * h + r;
      gm[mt][r] = fmaxf(fmaxf(redmax[0][row], redmax[1][row]),
                        fmaxf(redmax[2][row], redmax[3][row]));
      ps[mt][r] = 0.0f;
    }
  const float KS = 1.44269504088896340736f / 64.0f;   // log2(e)/SCALE
#pragma unroll
  for (int mt = 0; mt < 2; mt++)
#pragma unroll
    for (int nt = 0; nt < 4; nt++)
#pragma unroll
      for (int r = 0; r < 4; r++) {
        float e = exp2f((acc[mt][nt][r] - gm[mt][r]) * KS);
        acc[mt][nt][r] = e;
        ps[mt][r] += e;
      }
#pragma unroll
  for (int off = 1; off < 16; off <<= 1)
#pragma unroll
    for (int mt = 0; mt < 2; mt++)
#pragma unroll
      for (int r = 0; r < 4; r++) ps[mt][r] += __shfl_xor(ps[mt][r], off, 64);
  if (cl == 0) {
#pragma unroll
    for (int mt = 0; mt < 2; mt++)
#pragma unroll
      for (int r = 0; r < 4; r++) redsum[wv][mt * 16 + 4 * h + r] = ps[mt][r];
  }
  __syncthreads();

#pragma unroll
  for (int mt = 0; mt < 2; mt++)
#pragma unroll
    for (int r = 0; r < 4; r++) {
      int row = mt * 16 + 4 * h + r;
      float gs = redsum[0][row] + redsum[1][row] + redsum[2][row] + redsum[3][row];
      ps[mt][r] = 1.0f / gs;
    }
#pragma unroll
  for (int nt = 0; nt < 4; nt++) {
    int q = 64 * wv + nt * 16 + cl;
#pragma unroll
    for (int mt = 0; mt < 2; mt++)
#pragma unroll
      for (int r = 0; r < 4; r++) {
        int row = p0 + mt * 16 + 4 * h + r;
        attn[(size_t)bn * 65536 + row * 256 + q] = (bf16)(acc[mt][nt][r] * ps[mt][r]);
      }
  }
}

// ---------------- K2t: V transpose (token-major V -> Vq[bn][c][q]) ----------------
__global__ __launch_bounds__(256) void k2t_transpose(
    const bf16* __restrict__ Vtok, bf16* __restrict__ Vq)
{
  const int bx = blockIdx.x;
  const int bn = bx >> 7;
  const int q0 = ((bx >> 5) & 3) * 64;
  const int c0 = (bx & 31) * 64;           // c = sxy*32 + dk
  const int b = bn >> 3, n = bn & 7;
  __shared__ unsigned short tile[64][65];
  const unsigned short* src = (const unsigned short*)Vtok;
  unsigned short* dst = (unsigned short*)Vq + (size_t)bn * 524288;
  {
    const int q = threadIdx.x >> 3;            // 0..31
    const int cj = (threadIdx.x & 7) * 8;
    const int c = c0 + cj;
    const int sxy = c >> 5, dk0 = c & 31;
#pragma unroll
    for (int it = 0; it < 2; ++it) {
      int qq = q + it * 32;
      size_t sa = (size_t)((b * 256 + q0 + qq) * 64 + sxy) * 256 + n * 32 + dk0;
      ushort8 s = *reinterpret_cast<const ushort8*>(src + sa);
#pragma unroll
      for (int j = 0; j < 8; j++) tile[qq][cj + j] = s[j];
    }
  }
  __syncthreads();
  {
    const int crow = threadIdx.x >> 2;         // 0..63
    const int qj = (threadIdx.x & 3) * 8;
#pragma unroll
    for (int it = 0; it < 2; ++it) {
      int qq = qj + it * 32;
      ushort8 sv;
#pragma unroll
      for (int j = 0; j < 8; j++) sv[j] = tile[qq + j][crow];
      *reinterpret_cast<ushort8*>(dst + (size_t)(c0 + crow) * 256 + q0 + qq) = sv;
    }
  }
}

// ---------------- K2b: O = attn @ V ----------------
__global__ __launch_bounds__(256) void k2b_pv(
    const bf16* __restrict__ attn, const bf16* __restrict__ Vq,
    bf16* __restrict__ yhat)
{
  const int bx = blockIdx.x;
  const int bn = bx >> 5;
  const int p0 = ((bx >> 3) & 3) * 64;
  const int c0 = (bx & 7) * 256;
  const int b = bn >> 3, n = bn & 7;
  const int lane = threadIdx.x & 63;
  const int wv = threadIdx.x >> 6;
  const int h = lane >> 4, cl = lane & 15;

  const bf16* Ab = attn + (size_t)bn * 65536;
  const bf16* Vb = Vq + (size_t)bn * 524288;

  floatx4 acc[4][4];
#pragma unroll
  for (int i = 0; i < 4; i++)
#pragma unroll
    for (int j = 0; j < 4; j++) acc[i][j] = (floatx4)0.0f;

  for (int q0 = 0; q0 < 256; q0 += 32) {
    bf16x8 a[4];
#pragma unroll
    for (int mt = 0; mt < 4; mt++)
      a[mt] = *reinterpret_cast<const bf16x8*>(Ab + (size_t)(p0 + mt * 16 + cl) * 256 + q0 + 8 * h);
#pragma unroll
    for (int nt = 0; nt < 4; nt++) {
      bf16x8 b8 = *reinterpret_cast<const bf16x8*>(Vb + (size_t)(c0 + 64 * wv + nt * 16 + cl) * 256 + q0 + 8 * h);
#pragma unroll
      for (int mt = 0; mt < 4; mt++) acc[mt][nt] = mfma16(a[mt], b8, acc[mt][nt]);
    }
  }

#pragma unroll
  for (int nt = 0; nt < 4; nt++) {
    const int cg = c0 + 64 * wv + nt * 16 + cl;
    const int dk = cg & 31, sxy = cg >> 5;
#pragma unroll
    for (int mt = 0; mt < 4; mt++)
#pragma unroll
      for (int r = 0; r < 4; r++) {
        int p = p0 + mt * 16 + 4 * h + r;
        size_t t = (size_t)((b * 256 + p) * 64) + sxy;
        yhat[t * 256 + n * 32 + dk] = (bf16)acc[mt][nt][r];
      }
  }
}

// ---------------- K3: output projection ----------------
__global__ __launch_bounds__(256) void k3_out(
    const bf16* __restrict__ yhat, const bf16* __restrict__ Wo,
    const float* __restrict__ bo, float* __restrict__ outp)
{
  const int t0 = blockIdx.x * 64;
  const int lane = threadIdx.x & 63;
  const int wv = threadIdx.x >> 6;
  const int h = lane >> 4, cl = lane & 15;

  floatx4 acc[4][4];
#pragma unroll
  for (int i = 0; i < 4; i++)
#pragma unroll
    for (int j = 0; j < 4; j++) acc[i][j] = (floatx4)0.0f;

  for (int k0 = 0; k0 < 256; k0 += 32) {
    bf16x8 a[4];
#pragma unroll
    for (int mt = 0; mt < 4; mt++)
      a[mt] = *reinterpret_cast<const bf16x8*>(yhat + (size_t)(t0 + mt * 16 + cl) * 256 + k0 + 8 * h);
#pragma unroll
    for (int nt = 0; nt < 4; nt++) {
      bf16x8 b8 = *reinterpret_cast<const bf16x8*>(Wo + (size_t)(64 * wv + nt * 16 + cl) * 256 + k0 + 8 * h);
#pragma unroll
      for (int mt = 0; mt < 4; mt++) acc[mt][nt] = mfma16(a[mt], b8, acc[mt][nt]);
    }
  }

#pragma unroll
  for (int nt = 0; nt < 4; nt++) {
    const int j = 64 * wv + nt * 16 + cl;
    const float bb = bo[j];
#pragma unroll
    for (int mt = 0; mt < 4; mt++)
#pragma unroll
      for (int r = 0; r < 4; r++)
        outp[(size_t)(t0 + mt * 16 + 4 * h + r) * 256 + j] = acc[mt][nt][r] + bb;
  }
}

// ---------------- launch ----------------
extern "C" void kernel_launch(void* const* d_in, const int* in_sizes, int n_in,
                              void* d_out, int out_size, void* d_ws, size_t ws_size,
                              hipStream_t stream) {
  const float* x  = (const float*)d_in[0];
  const float* Wq = (const float*)d_in[1];
  const float* bq = (const float*)d_in[2];
  const float* Wk = (const float*)d_in[3];
  const float* bk = (const float*)d_in[4];
  const float* Wv = (const float*)d_in[5];
  const float* bv = (const float*)d_in[6];
  const float* Wo = (const float*)d_in[7];
  const float* bo = (const float*)d_in[8];
  float* outp = (float*)d_out;

  char* ws = (char*)d_ws;
  const size_t SZ_QKV = 67108864;   // 131072*256 * 2B
  size_t off = 0;
  bf16* Qt   = (bf16*)(ws + off); off += SZ_QKV;
  bf16* Kt   = (bf16*)(ws + off); off += SZ_QKV;
  bf16* Vtok = (bf16*)(ws + off); off += SZ_QKV;
  bf16* attn = (bf16*)(ws + off); off += 8388608;
  bf16* Wp   = (bf16*)(ws + off); off += 393216;   // 3 mats packed
  bf16* WOp  = (bf16*)(ws + off); off += 131072;
  float* biasp = (float*)(ws + off); off += 3072;
  if (ws_size < off) return;        // workspace too small: bail cleanly

  bf16* yhat = Qt;                  // Qt dead after k2a
  bf16* Vq   = Kt;                  // Kt dead after k2a (k2t runs after k2a)

  k0_prep<<<64, 256, 0, stream>>>(Wq, bq, Wk, bk, Wv, bv, Wo, Wp, WOp, biasp);
  k1_qkv<<<2048, 256, 0, stream>>>(x, Wp, biasp, Qt, Kt, Vtok);
  k2a_scores<<<512, 256, 0, stream>>>(Qt, Kt, attn);
  k2t_transpose<<<8192, 256, 0, stream>>>(Vtok, Vq);
  k2b_pv<<<2048, 256, 0, stream>>>(attn, Vq, yhat);
  k3_out<<<2048, 256, 0, stream>>>(yhat, WOp, bo, outp);
}

// Round 5
// 413.110 us; speedup vs baseline: 1.1015x; 1.1015x over previous
//
#include <hip/hip_runtime.h>
#include <hip/hip_bf16.h>

// MultiheadAttention_ViTNO: B=8, P=256, S=8x8(=64), D=256, NHEAD=8, DK=32, SCALE=64
// R5: k1 occupancy fix. R3/R4 lesson: unified VGPR+AGPR file pinned k1 at
// 2 waves/SIMD (R3: 128V+96A=224/wave; R4: 128V+192A=320/wave) -> 80% of time
// zero issue (MfmaUtil 10% == the 20us MFMA floor smeared over 200us).
// New k1: block=512thr/8 waves, one mat per block (grid y=3), wave = 32-col
// slice -> acc[4][2]=32 regs, ~76 total/wave, __launch_bounds__(512,6) ->
// target 24 waves/CU (75%). Staging + swizzle + Wp layout identical to R4.

typedef __bf16 bf16;
typedef __attribute__((ext_vector_type(8))) __bf16 bf16x8;
typedef __attribute__((ext_vector_type(4))) float floatx4;
typedef __attribute__((ext_vector_type(8))) unsigned short ushort8;

#define CDIM 2048             // 64*32 flattened (sxy, dk) per head

static __device__ __forceinline__ floatx4 mfma16(bf16x8 a, bf16x8 b, floatx4 c) {
  return __builtin_amdgcn_mfma_f32_16x16x32_bf16(a, b, c, 0, 0, 0);
}

// ---------------- K0: weight prep ----------------
// Wp: fragment-linear pack of Wq/Wk/Wv (head-permuted rows i'=n*32+dk):
//   Wp[((mat*8 + kk)*16 + rowblk)*64 + lane]*8 ; lane=(h,cl):
//   element = Wperm[rowblk*16+cl][kk*32+8h+j]
// WOp: row-major [j][i'-permuted col] for k3. biasp[3][256] permuted.
__global__ __launch_bounds__(256) void k0_prep(
    const float* __restrict__ Wq, const float* __restrict__ bq,
    const float* __restrict__ Wk, const float* __restrict__ bk,
    const float* __restrict__ Wv, const float* __restrict__ bv,
    const float* __restrict__ Wo,
    bf16* __restrict__ Wp, bf16* __restrict__ WOp, float* __restrict__ biasp)
{
  const int bid = blockIdx.x, tid = threadIdx.x;
  if (bid < 32) {
    int g = bid * 256 + tid;            // 0..8191 : (kk, rowblk, lane)
    int lane = g & 63, rowblk = (g >> 6) & 15, kk = g >> 10;
    int h = lane >> 4, cl = lane & 15;
    int ip = rowblk * 16 + cl;          // i' = n*32+dk
    int isrc = ((ip & 31) << 3) | (ip >> 5);
    int d0 = kk * 32 + 8 * h;
#pragma unroll
    for (int mat = 0; mat < 3; mat++) {
      const float* W = (mat == 0) ? Wq : (mat == 1) ? Wk : Wv;
      bf16x8 v;
#pragma unroll
      for (int j = 0; j < 8; j++) v[j] = (bf16)W[isrc * 256 + d0 + j];
      *reinterpret_cast<bf16x8*>(Wp + ((size_t)mat * 8192 + g) * 8) = v;
    }
  } else {
    int g = (bid - 32) * 256 + tid;     // 0..8191
    int row = g >> 5;
    int c0 = (g & 31) * 8;
#pragma unroll
    for (int j = 0; j < 8; j++) {
      int c = c0 + j;
      WOp[row * 256 + c] = (bf16)Wo[row * 256 + (((c & 31) << 3) | (c >> 5))];
    }
    if (g < 256) {
      int bs = ((g & 31) << 3) | (g >> 5);
      biasp[g] = bq[bs]; biasp[256 + g] = bk[bs]; biasp[512 + g] = bv[bs];
    }
  }
}

// ---------------- K1: QKV projection, one mat per block ----------------
// grid (2048, 3); block 512 (8 waves, each a 32-col slice). Tile: 64 tokens.
// Out token-major: Q/K/V[t][i'] bf16, t=(b,p,sxy).
__global__ __launch_bounds__(512, 6) void k1_qkv(
    const float* __restrict__ x, const bf16* __restrict__ Wp,
    const float* __restrict__ biasp,
    bf16* __restrict__ Qt, bf16* __restrict__ Kt, bf16* __restrict__ Vt)
{
  __shared__ bf16 xsb[64 * 256];        // 32KB, granule-XOR-swizzled (as R4)
  const int t0 = blockIdx.x * 64;
  const int mat = blockIdx.y;
  const int tid = threadIdx.x;
  const int lane = tid & 63;
  const int w = tid >> 6;               // wave 0..7 -> ip slice [w*32, w*32+32)
  const int h = lane >> 4, cl = lane & 15;
  const int c7 = cl & 7;

  const bf16* Wm = Wp + (size_t)mat * 65536;   // this mat's fragment pack
  bf16* out = (mat == 0) ? Qt : (mat == 1) ? Kt : Vt;

  // stage: 2048 granules (16B); granule G: row=G>>5, coalesced fp32 src,
  // cvt to bf16, write to physical granule (G&~7)|((G^row)&7)
#pragma unroll
  for (int k = 0; k < 4; ++k) {
    int G = k * 512 + tid;
    int row = G >> 5;
    const float* sp = x + (size_t)(t0 + row) * 256 + (G & 31) * 8;
    floatx4 f0 = *reinterpret_cast<const floatx4*>(sp);
    floatx4 f1 = *reinterpret_cast<const floatx4*>(sp + 4);
    bf16x8 v;
#pragma unroll
    for (int j = 0; j < 4; j++) { v[j] = (bf16)f0[j]; v[4 + j] = (bf16)f1[j]; }
    int Gp = (G & ~7) | ((G ^ row) & 7);
    *reinterpret_cast<bf16x8*>(&xsb[Gp * 8]) = v;
  }
  __syncthreads();

  floatx4 acc[4][2];
#pragma unroll
  for (int i = 0; i < 4; i++)
#pragma unroll
    for (int j = 0; j < 2; j++) acc[i][j] = (floatx4)0.0f;

#pragma unroll 2
  for (int kk = 0; kk < 8; ++kk) {
    bf16x8 a[4];
#pragma unroll
    for (int mt = 0; mt < 4; mt++) {
      int rr = mt * 16 + cl;            // rr&7 == c7
      int G = rr * 32 + kk * 4 + h;
      int Gp = (G & ~7) | ((G ^ c7) & 7);
      a[mt] = *reinterpret_cast<const bf16x8*>(&xsb[Gp * 8]);
    }
    bf16x8 b0 = *reinterpret_cast<const bf16x8*>(
        Wm + ((size_t)(kk * 16 + w * 2 + 0) * 64 + lane) * 8);
    bf16x8 b1 = *reinterpret_cast<const bf16x8*>(
        Wm + ((size_t)(kk * 16 + w * 2 + 1) * 64 + lane) * 8);
#pragma unroll
    for (int mt = 0; mt < 4; mt++) acc[mt][0] = mfma16(a[mt], b0, acc[mt][0]);
#pragma unroll
    for (int mt = 0; mt < 4; mt++) acc[mt][1] = mfma16(a[mt], b1, acc[mt][1]);
  }

  // token-major epilogue (32B-contiguous per 16 cl lanes)
#pragma unroll
  for (int nt = 0; nt < 2; nt++) {
    const int ip = w * 32 + nt * 16 + cl;
    const float bb = biasp[mat * 256 + ip];
#pragma unroll
    for (int mt = 0; mt < 4; mt++)
#pragma unroll
      for (int r = 0; r < 4; r++) {
        int t = t0 + mt * 16 + 4 * h + r;
        out[(size_t)t * 256 + ip] = (bf16)(acc[mt][nt][r] + bb);
      }
  }
}

// ---------------- K2a: scores + softmax ----------------
// grid 512 (= 64 bn * 8 ptiles of 32); block 256. attn[bn][p][q] bf16.
__global__ __launch_bounds__(256) void k2a_scores(
    const bf16* __restrict__ Qt, const bf16* __restrict__ Kt,
    bf16* __restrict__ attn)
{
  const int bx = blockIdx.x;
  const int bn = bx >> 3;
  const int p0 = (bx & 7) * 32;
  const int b = bn >> 3, n = bn & 7;
  const int lane = threadIdx.x & 63;
  const int wv = threadIdx.x >> 6;
  const int h = lane >> 4, cl = lane & 15;

  const bf16* qp[2];
#pragma unroll
  for (int mt = 0; mt < 2; mt++)
    qp[mt] = Qt + (size_t)((b * 256 + p0 + mt * 16 + cl) * 64) * 256 + n * 32 + 8 * h;
  const bf16* kp[4];
#pragma unroll
  for (int nt = 0; nt < 4; nt++)
    kp[nt] = Kt + (size_t)((b * 256 + 64 * wv + nt * 16 + cl) * 64) * 256 + n * 32 + 8 * h;

  floatx4 acc[2][4];
#pragma unroll
  for (int i = 0; i < 2; i++)
#pragma unroll
    for (int j = 0; j < 4; j++) acc[i][j] = (floatx4)0.0f;

#pragma unroll 4
  for (int ks = 0; ks < 64; ks++) {
    bf16x8 a[2], bb[4];
#pragma unroll
    for (int mt = 0; mt < 2; mt++) {
      a[mt] = *reinterpret_cast<const bf16x8*>(qp[mt]); qp[mt] += 256;
    }
#pragma unroll
    for (int nt = 0; nt < 4; nt++) {
      bb[nt] = *reinterpret_cast<const bf16x8*>(kp[nt]); kp[nt] += 256;
    }
#pragma unroll
    for (int nt = 0; nt < 4; nt++)
#pragma unroll
      for (int mt = 0; mt < 2; mt++) acc[mt][nt] = mfma16(a[mt], bb[nt], acc[mt][nt]);
  }

  __shared__ float redmax[4][32];
  __shared__ float redsum[4][32];

  float pm[2][4];
#pragma unroll
  for (int mt = 0; mt < 2; mt++)
#pragma unroll
    for (int r = 0; r < 4; r++)
      pm[mt][r] = fmaxf(fmaxf(acc[mt][0][r], acc[mt][1][r]),
                        fmaxf(acc[mt][2][r], acc[mt][3][r]));
#pragma unroll
  for (int off = 1; off < 16; off <<= 1)
#pragma unroll
    for (int mt = 0; mt < 2; mt++)
#pragma unroll
      for (int r = 0; r < 4; r++)
        pm[mt][r] = fmaxf(pm[mt][r], __shfl_xor(pm[mt][r], off, 64));
  if (cl == 0) {
#pragma unroll
    for (int mt = 0; mt < 2; mt++)
#pragma unroll
      for (int r = 0; r < 4; r++) redmax[wv][mt * 16 + 4 * h + r] = pm[mt][r];
  }
  __syncthreads();

  float gm[2][4], ps[2][4];
#pragma unroll
  for (int mt = 0; mt < 2; mt++)
#pragma unroll
    for (int r = 0; r < 4; r++) {
      int row = mt * 16 + 4 * h + r;
      gm[mt][r] = fmaxf(fmaxf(redmax[0][row], redmax[1][row]),
                        fmaxf(redmax[2][row], redmax[3][row]));
      ps[mt][r] = 0.0f;
    }
  const float KS = 1.44269504088896340736f / 64.0f;   // log2(e)/SCALE
#pragma unroll
  for (int mt = 0; mt < 2; mt++)
#pragma unroll
    for (int nt = 0; nt < 4; nt++)
#pragma unroll
      for (int r = 0; r < 4; r++) {
        float e = exp2f((acc[mt][nt][r] - gm[mt][r]) * KS);
        acc[mt][nt][r] = e;
        ps[mt][r] += e;
      }
#pragma unroll
  for (int off = 1; off < 16; off <<= 1)
#pragma unroll
    for (int mt = 0; mt < 2; mt++)
#pragma unroll
      for (int r = 0; r < 4; r++) ps[mt][r] += __shfl_xor(ps[mt][r], off, 64);
  if (cl == 0) {
#pragma unroll
    for (int mt = 0; mt < 2; mt++)
#pragma unroll
      for (int r = 0; r < 4; r++) redsum[wv][mt * 16 + 4 * h + r] = ps[mt][r];
  }
  __syncthreads();

#pragma unroll
  for (int mt = 0; mt < 2; mt++)
#pragma unroll
    for (int r = 0; r < 4; r++) {
      int row = mt * 16 + 4 * h + r;
      float gs = redsum[0][row] + redsum[1][row] + redsum[2][row] + redsum[3][row];
      ps[mt][r] = 1.0f / gs;
    }
#pragma unroll
  for (int nt = 0; nt < 4; nt++) {
    int q = 64 * wv + nt * 16 + cl;
#pragma unroll
    for (int mt = 0; mt < 2; mt++)
#pragma unroll
      for (int r = 0; r < 4; r++) {
        int row = p0 + mt * 16 + 4 * h + r;
        attn[(size_t)bn * 65536 + row * 256 + q] = (bf16)(acc[mt][nt][r] * ps[mt][r]);
      }
  }
}

// ---------------- K2t: V transpose (token-major V -> Vq[bn][c][q]) ----------------
__global__ __launch_bounds__(256) void k2t_transpose(
    const bf16* __restrict__ Vtok, bf16* __restrict__ Vq)
{
  const int bx = blockIdx.x;
  const int bn = bx >> 7;
  const int q0 = ((bx >> 5) & 3) * 64;
  const int c0 = (bx & 31) * 64;           // c = sxy*32 + dk
  const int b = bn >> 3, n = bn & 7;
  __shared__ unsigned short tile[64][65];
  const unsigned short* src = (const unsigned short*)Vtok;
  unsigned short* dst = (unsigned short*)Vq + (size_t)bn * 524288;
  {
    const int q = threadIdx.x >> 3;            // 0..31
    const int cj = (threadIdx.x & 7) * 8;
    const int c = c0 + cj;
    const int sxy = c >> 5, dk0 = c & 31;
#pragma unroll
    for (int it = 0; it < 2; ++it) {
      int qq = q + it * 32;
      size_t sa = (size_t)((b * 256 + q0 + qq) * 64 + sxy) * 256 + n * 32 + dk0;
      ushort8 s = *reinterpret_cast<const ushort8*>(src + sa);
#pragma unroll
      for (int j = 0; j < 8; j++) tile[qq][cj + j] = s[j];
    }
  }
  __syncthreads();
  {
    const int crow = threadIdx.x >> 2;         // 0..63
    const int qj = (threadIdx.x & 3) * 8;
#pragma unroll
    for (int it = 0; it < 2; ++it) {
      int qq = qj + it * 32;
      ushort8 sv;
#pragma unroll
      for (int j = 0; j < 8; j++) sv[j] = tile[qq + j][crow];
      *reinterpret_cast<ushort8*>(dst + (size_t)(c0 + crow) * 256 + q0 + qq) = sv;
    }
  }
}

// ---------------- K2b: O = attn @ V ----------------
__global__ __launch_bounds__(256) void k2b_pv(
    const bf16* __restrict__ attn, const bf16* __restrict__ Vq,
    bf16* __restrict__ yhat)
{
  const int bx = blockIdx.x;
  const int bn = bx >> 5;
  const int p0 = ((bx >> 3) & 3) * 64;
  const int c0 = (bx & 7) * 256;
  const int b = bn >> 3, n = bn & 7;
  const int lane = threadIdx.x & 63;
  const int wv = threadIdx.x >> 6;
  const int h = lane >> 4, cl = lane & 15;

  const bf16* Ab = attn + (size_t)bn * 65536;
  const bf16* Vb = Vq + (size_t)bn * 524288;

  floatx4 acc[4][4];
#pragma unroll
  for (int i = 0; i < 4; i++)
#pragma unroll
    for (int j = 0; j < 4; j++) acc[i][j] = (floatx4)0.0f;

  for (int q0 = 0; q0 < 256; q0 += 32) {
    bf16x8 a[4];
#pragma unroll
    for (int mt = 0; mt < 4; mt++)
      a[mt] = *reinterpret_cast<const bf16x8*>(Ab + (size_t)(p0 + mt * 16 + cl) * 256 + q0 + 8 * h);
#pragma unroll
    for (int nt = 0; nt < 4; nt++) {
      bf16x8 b8 = *reinterpret_cast<const bf16x8*>(Vb + (size_t)(c0 + 64 * wv + nt * 16 + cl) * 256 + q0 + 8 * h);
#pragma unroll
      for (int mt = 0; mt < 4; mt++) acc[mt][nt] = mfma16(a[mt], b8, acc[mt][nt]);
    }
  }

#pragma unroll
  for (int nt = 0; nt < 4; nt++) {
    const int cg = c0 + 64 * wv + nt * 16 + cl;
    const int dk = cg & 31, sxy = cg >> 5;
#pragma unroll
    for (int mt = 0; mt < 4; mt++)
#pragma unroll
      for (int r = 0; r < 4; r++) {
        int p = p0 + mt * 16 + 4 * h + r;
        size_t t = (size_t)((b * 256 + p) * 64) + sxy;
        yhat[t * 256 + n * 32 + dk] = (bf16)acc[mt][nt][r];
      }
  }
}

// ---------------- K3: output projection ----------------
__global__ __launch_bounds__(256) void k3_out(
    const bf16* __restrict__ yhat, const bf16* __restrict__ Wo,
    const float* __restrict__ bo, float* __restrict__ outp)
{
  const int t0 = blockIdx.x * 64;
  const int lane = threadIdx.x & 63;
  const int wv = threadIdx.x >> 6;
  const int h = lane >> 4, cl = lane & 15;

  floatx4 acc[4][4];
#pragma unroll
  for (int i = 0; i < 4; i++)
#pragma unroll
    for (int j = 0; j < 4; j++) acc[i][j] = (floatx4)0.0f;

  for (int k0 = 0; k0 < 256; k0 += 32) {
    bf16x8 a[4];
#pragma unroll
    for (int mt = 0; mt < 4; mt++)
      a[mt] = *reinterpret_cast<const bf16x8*>(yhat + (size_t)(t0 + mt * 16 + cl) * 256 + k0 + 8 * h);
#pragma unroll
    for (int nt = 0; nt < 4; nt++) {
      bf16x8 b8 = *reinterpret_cast<const bf16x8*>(Wo + (size_t)(64 * wv + nt * 16 + cl) * 256 + k0 + 8 * h);
#pragma unroll
      for (int mt = 0; mt < 4; mt++) acc[mt][nt] = mfma16(a[mt], b8, acc[mt][nt]);
    }
  }

#pragma unroll
  for (int nt = 0; nt < 4; nt++) {
    const int j = 64 * wv + nt * 16 + cl;
    const float bb = bo[j];
#pragma unroll
    for (int mt = 0; mt < 4; mt++)
#pragma unroll
      for (int r = 0; r < 4; r++)
        outp[(size_t)(t0 + mt * 16 + 4 * h + r) * 256 + j] = acc[mt][nt][r] + bb;
  }
}

// ---------------- launch ----------------
extern "C" void kernel_launch(void* const* d_in, const int* in_sizes, int n_in,
                              void* d_out, int out_size, void* d_ws, size_t ws_size,
                              hipStream_t stream) {
  const float* x  = (const float*)d_in[0];
  const float* Wq = (const float*)d_in[1];
  const float* bq = (const float*)d_in[2];
  const float* Wk = (const float*)d_in[3];
  const float* bk = (const float*)d_in[4];
  const float* Wv = (const float*)d_in[5];
  const float* bv = (const float*)d_in[6];
  const float* Wo = (const float*)d_in[7];
  const float* bo = (const float*)d_in[8];
  float* outp = (float*)d_out;

  char* ws = (char*)d_ws;
  const size_t SZ_QKV = 67108864;   // 131072*256 * 2B
  size_t off = 0;
  bf16* Qt   = (bf16*)(ws + off); off += SZ_QKV;
  bf16* Kt   = (bf16*)(ws + off); off += SZ_QKV;
  bf16* Vtok = (bf16*)(ws + off); off += SZ_QKV;
  bf16* attn = (bf16*)(ws + off); off += 8388608;
  bf16* Wp   = (bf16*)(ws + off); off += 393216;   // 3 mats packed
  bf16* WOp  = (bf16*)(ws + off); off += 131072;
  float* biasp = (float*)(ws + off); off += 3072;
  if (ws_size < off) return;        // workspace too small: bail cleanly

  bf16* yhat = Qt;                  // Qt dead after k2a
  bf16* Vq   = Kt;                  // Kt dead after k2a (k2t runs after k2a)

  k0_prep<<<64, 256, 0, stream>>>(Wq, bq, Wk, bk, Wv, bv, Wo, Wp, WOp, biasp);
  k1_qkv<<<dim3(2048, 3), 512, 0, stream>>>(x, Wp, biasp, Qt, Kt, Vtok);
  k2a_scores<<<512, 256, 0, stream>>>(Qt, Kt, attn);
  k2t_transpose<<<8192, 256, 0, stream>>>(Vtok, Vq);
  k2b_pv<<<2048, 256, 0, stream>>>(attn, Vq, yhat);
  k3_out<<<2048, 256, 0, stream>>>(yhat, WOp, bo, outp);
}